// Round 13
// baseline (129.085 us; speedup 1.0000x reference)
//
#include <hip/hip_runtime.h>
#include <math.h>

#define NHEAD 8
#define HEAD_DIM 32
#define IMG_H 32
#define IMG_W 40
#define NPIX (IMG_H*IMG_W)
#define CMAX 160
#define FEAT (NHEAD*HEAD_DIM)

// ===== R13: CONTROLLED fp32 emulation (R12 resubmit; R12 = infra fail) =====
// R11 finding: __f*_rn are plain operators in HIP headers and hipcc's
// default -ffp-contract=fast fused my "chain" code nondeterministically
// (two provably-identical kernels -> different absmax). Fix: every FP
// helper runs under `#pragma clang fp contract(off)`; FMA appears only as
// explicit __builtin_fmaf. Cell under test: faithful numpy =
//   M1 chain (swapaxes view fails is_blasable2d -> noblas loop)
//   M2 chain (T1 @ I — exact either way)
//   M3 sgemm-FMA ascending (contiguous operands -> OpenBLAS)
//   einsum chain, cc chain (ufunc/SOP loops can't contract)
#define M3_FMA        1
#define EINSUM_FMA    0
#define CC_FMA        0

// np.linalg.inv (f32) — LAPACK LU, true divides; bit-forced for this K
// (div == recip-mul verified by hand for 1/35, 16/35, 4/7 cases).
__device__ void np_inv3x3_f32(const float* M, float inv[3][3]) {
#pragma clang fp contract(off)
    float A[3][3]; int piv[3];
    for (int i=0;i<3;i++) { A[i][0]=M[i*3+0]; A[i][1]=M[i*3+1]; A[i][2]=M[i*3+2]; }
    for (int kk=0;kk<3;kk++) {
        int p = kk;
        float colmax = fabsf(A[kk][kk]);
        for (int i=kk+1;i<3;i++) { float vv=fabsf(A[i][kk]); if (vv>colmax){colmax=vv;p=i;} }
        piv[kk] = p;
        if (p!=kk) { for(int j=0;j<3;j++){float tmp=A[kk][j];A[kk][j]=A[p][j];A[p][j]=tmp;} }
        const float rp = 1.0f / A[kk][kk];
        for (int i=kk+1;i<3;i++) A[i][kk] = A[i][kk] * rp;
        for (int i=kk+1;i<3;i++)
            for (int j=kk+1;j<3;j++)
                A[i][j] = A[i][j] - A[i][kk]*A[kk][j];
    }
    for (int col=0; col<3; col++) {
        float b[3] = {0.f,0.f,0.f}; b[col] = 1.0f;
        for (int kk=0;kk<3;kk++) if (piv[kk]!=kk) { float tmp=b[kk]; b[kk]=b[piv[kk]]; b[piv[kk]]=tmp; }
        for (int i=1;i<3;i++)
            for (int kk=0;kk<i;kk++)
                b[i] = b[i] - A[i][kk]*b[kk];
        for (int kk=2;kk>=0;kk--) {
            b[kk] = b[kk] / A[kk][kk];
            for (int i=0;i<kk;i++)
                b[i] = b[i] - A[i][kk]*b[kk];
        }
        inv[0][col]=b[0]; inv[1][col]=b[1]; inv[2][col]=b[2];
    }
}

// noblas chain: mul+add, ascending k, contraction OFF
__device__ void mm3_chain(const float A[3][3], const float B[3][3], float C[3][3]) {
#pragma clang fp contract(off)
    for (int i=0;i<3;i++)
        for (int j=0;j<3;j++) {
            float acc = A[i][0]*B[0][j];
            acc = acc + A[i][1]*B[1][j];
            acc = acc + A[i][2]*B[2][j];
            C[i][j] = acc;
        }
}
// sgemm microkernel: acc from first product, explicit FMA ascending k
__device__ void mm3_fma(const float A[3][3], const float B[3][3], float C[3][3]) {
#pragma clang fp contract(off)
    for (int i=0;i<3;i++)
        for (int j=0;j<3;j++) {
            float acc = A[i][0]*B[0][j];
            acc = __builtin_fmaf(A[i][1], B[1][j], acc);
            acc = __builtin_fmaf(A[i][2], B[2][j], acc);
            C[i][j] = acc;
        }
}

// einsum row: F[i][0]*x + F[i][1]*y + F[i][2]*1, ascending j
__device__ float einsum_row(const float Fi[3], float x, float y) {
#pragma clang fp contract(off)
#if EINSUM_FMA
    float acc = Fi[0]*x;
    acc = __builtin_fmaf(Fi[1], y, acc);
    acc = acc + Fi[2];
    return acc;
#else
    float acc = Fi[0]*x;
    acc = acc + Fi[1]*y;
    acc = acc + Fi[2]*1.0f;
    return acc;
#endif
}

__global__ __launch_bounds__(256) void one2many_attn(
    const float* __restrict__ q, const float* __restrict__ k, const float* __restrict__ v,
    const float* __restrict__ K0, const float* __restrict__ K1,
    const float* __restrict__ R, const float* __restrict__ t,
    float* __restrict__ out)
{
#pragma clang fp contract(off)
    __shared__ float s_q[FEAT];
    __shared__ float s_sc[NHEAD][CMAX];
    __shared__ int   s_cand[CMAX];
    __shared__ int   s_cnt;

    const int l   = blockIdx.x;
    const int tid = threadIdx.x;

    if (tid == 0) s_cnt = 0;
    s_q[tid] = q[l*FEAT + tid];

    // ---- geometry: controlled fp32 pipeline ----
    float i0[3][3], i1[3][3], A[3][3], B[3][3], T1[3][3], T2[3][3], F[3][3], Rm[3][3];
    np_inv3x3_f32(K0, i0);
    np_inv3x3_f32(K1, i1);
    for (int i=0;i<3;i++)
        for (int j=0;j<3;j++) { A[i][j] = i1[j][i]; Rm[i][j] = R[i*3+j]; }
    const float t0=t[0], t1=t[1], t2=t[2];
    B[0][0]=0.f;  B[0][1]=-t2;  B[0][2]=t1;
    B[1][0]=t2;   B[1][1]=0.f;  B[1][2]=-t0;
    B[2][0]=-t1;  B[2][1]=t0;   B[2][2]=0.f;
    mm3_chain(A,B,T1);          // transposed-view slice -> numpy noblas
    mm3_chain(T1,Rm,T2);        // T1 @ I (exact under either semantics)
#if M3_FMA
    mm3_fma(T2,i0,F);           // contiguous -> OpenBLAS sgemm FMA
#else
    mm3_chain(T2,i0,F);
#endif

    const float xl = (float)(l % IMG_W);
    const float yl = (float)(l / IMG_W);
    const float la = einsum_row(F[0], xl, yl);
    const float lb = einsum_row(F[1], xl, yl);
    const float lc = einsum_row(F[2], xl, yl);
    const bool  mode  = fabsf(lb) > fabsf(la);
    const float denom = mode ? lb : la;
    const float slope = (mode ? -la : -lb) / denom;
    const float icpt  = (-lc) / denom;

    __syncthreads();   // s_cnt=0 visible

    // ---- candidate collection: fp32 open-band test (m==0 ref-invalid) ----
    for (int m = tid; m < NPIX; m += 256) {
        const float xm = (float)(m % IMG_W), ym = (float)(m / IMG_W);
        const float tin  = mode ? xm : ym;
        const float tchk = mode ? ym : xm;
#if CC_FMA
        const float cc = __builtin_fmaf(slope, tin, icpt);
#else
        const float mu = slope * tin;
        const float cc = mu + icpt;
#endif
        const float hi = cc + 2.0f;
        const float lo = cc - 2.0f;
        if ((tchk < hi) && (tchk > lo) && m != 0) {
            int pos = atomicAdd(&s_cnt, 1);
            if (pos < CMAX) s_cand[pos] = m;   // open-4 band: <=4/column x 40 = 160 max
        }
    }
    __syncthreads();
    const int nc = min(s_cnt, CMAX);

    const int h = tid >> 5;          // head group (32 lanes, half-wave)
    const int j = tid & 31;

    // ---- QK: lane dots q[h,:] (LDS) with contiguous 128B k rows ----
    const float* qh = s_q + h*HEAD_DIM;
    for (int c = j; c < nc; c += 32) {
        const float4* kr = (const float4*)(k + (size_t)s_cand[c]*FEAT + h*HEAD_DIM);
        float acc = 0.f;
        #pragma unroll
        for (int u = 0; u < 8; u++) {
            const float4 kk = kr[u];
            acc = __builtin_fmaf(qh[4*u+0], kk.x, acc);
            acc = __builtin_fmaf(qh[4*u+1], kk.y, acc);
            acc = __builtin_fmaf(qh[4*u+2], kk.z, acc);
            acc = __builtin_fmaf(qh[4*u+3], kk.w, acc);
        }
        s_sc[h][c] = acc * 0.17677669529663687f;   // 1/sqrt(32)
    }
    __syncthreads();

    // ---- softmax per head (32-lane shuffle reduce) ----
    float mx = -INFINITY;
    for (int c = j; c < nc; c += 32) mx = fmaxf(mx, s_sc[h][c]);
    #pragma unroll
    for (int o = 16; o; o >>= 1) mx = fmaxf(mx, __shfl_xor(mx, o));
    float sum = 0.f;
    for (int c = j; c < nc; c += 32) {
        const float e = __expf(s_sc[h][c] - mx);
        s_sc[h][c] = e;
        sum += e;
    }
    #pragma unroll
    for (int o = 16; o; o >>= 1) sum += __shfl_xor(sum, o);
    __syncthreads();

    // ---- AV: lane j = output dim; coalesced v row gathers ----
    const float* vp = v + h*HEAD_DIM + j;
    float acc = 0.f;
    #pragma unroll 4
    for (int c = 0; c < nc; c++)
        acc = __builtin_fmaf(s_sc[h][c], vp[(size_t)s_cand[c]*FEAT], acc);

    out[l*FEAT + tid] = (nc > 0) ? acc / sum : 0.0f;
}

extern "C" void kernel_launch(void* const* d_in, const int* in_sizes, int n_in,
                              void* d_out, int out_size, void* d_ws, size_t ws_size,
                              hipStream_t stream) {
    const float* q  = (const float*)d_in[0];
    const float* k  = (const float*)d_in[1];
    const float* v  = (const float*)d_in[2];
    const float* K0 = (const float*)d_in[3];
    const float* K1 = (const float*)d_in[4];
    const float* R  = (const float*)d_in[5];
    const float* t  = (const float*)d_in[6];
    float* out = (float*)d_out;
    one2many_attn<<<NPIX, 256, 0, stream>>>(q, k, v, K0, K1, R, t, out);
}

// Round 14
// 127.918 us; speedup vs baseline: 1.0091x; 1.0091x over previous
//
#include <hip/hip_runtime.h>
#include <math.h>

#define NHEAD 8
#define HEAD_DIM 32
#define IMG_H 32
#define IMG_W 40
#define NPIX (IMG_H*IMG_W)
#define CMAX 160
#define FEAT (NHEAD*HEAD_DIM)

// ===== Geometry: LOCKED bit-exact numpy-fp32 emulation (R13 PASSED) =====
// M1 chain (swapaxes view -> noblas), M2 chain (T1@I), M3 sgemm-FMA,
// einsum chain, cc chain; ALL under `#pragma clang fp contract(off)`,
// FMA only via __builtin_fmaf. DO NOT TOUCH the semantics below.

__device__ void np_inv3x3_f32(const float* M, float inv[3][3]) {
#pragma clang fp contract(off)
    float A[3][3]; int piv[3];
    for (int i=0;i<3;i++) { A[i][0]=M[i*3+0]; A[i][1]=M[i*3+1]; A[i][2]=M[i*3+2]; }
    for (int kk=0;kk<3;kk++) {
        int p = kk;
        float colmax = fabsf(A[kk][kk]);
        for (int i=kk+1;i<3;i++) { float vv=fabsf(A[i][kk]); if (vv>colmax){colmax=vv;p=i;} }
        piv[kk] = p;
        if (p!=kk) { for(int j=0;j<3;j++){float tmp=A[kk][j];A[kk][j]=A[p][j];A[p][j]=tmp;} }
        const float rp = 1.0f / A[kk][kk];
        for (int i=kk+1;i<3;i++) A[i][kk] = A[i][kk] * rp;
        for (int i=kk+1;i<3;i++)
            for (int j=kk+1;j<3;j++)
                A[i][j] = A[i][j] - A[i][kk]*A[kk][j];
    }
    for (int col=0; col<3; col++) {
        float b[3] = {0.f,0.f,0.f}; b[col] = 1.0f;
        for (int kk=0;kk<3;kk++) if (piv[kk]!=kk) { float tmp=b[kk]; b[kk]=b[piv[kk]]; b[piv[kk]]=tmp; }
        for (int i=1;i<3;i++)
            for (int kk=0;kk<i;kk++)
                b[i] = b[i] - A[i][kk]*b[kk];
        for (int kk=2;kk>=0;kk--) {
            b[kk] = b[kk] / A[kk][kk];
            for (int i=0;i<kk;i++)
                b[i] = b[i] - A[i][kk]*b[kk];
        }
        inv[0][col]=b[0]; inv[1][col]=b[1]; inv[2][col]=b[2];
    }
}

__device__ void mm3_chain(const float A[3][3], const float B[3][3], float C[3][3]) {
#pragma clang fp contract(off)
    for (int i=0;i<3;i++)
        for (int j=0;j<3;j++) {
            float acc = A[i][0]*B[0][j];
            acc = acc + A[i][1]*B[1][j];
            acc = acc + A[i][2]*B[2][j];
            C[i][j] = acc;
        }
}
__device__ void mm3_fma(const float A[3][3], const float B[3][3], float C[3][3]) {
#pragma clang fp contract(off)
    for (int i=0;i<3;i++)
        for (int j=0;j<3;j++) {
            float acc = A[i][0]*B[0][j];
            acc = __builtin_fmaf(A[i][1], B[1][j], acc);
            acc = __builtin_fmaf(A[i][2], B[2][j], acc);
            C[i][j] = acc;
        }
}
__device__ float einsum_row(const float Fi[3], float x, float y) {
#pragma clang fp contract(off)
    float acc = Fi[0]*x;
    acc = acc + Fi[1]*y;
    acc = acc + Fi[2]*1.0f;
    return acc;
}

// ===== R14: head-per-wave restructure (perf only; geometry untouched) =====
// 512 thr = 8 waves = 8 heads per query pixel. 10240 waves -> 32/CU
// (was 20/CU). QK: 24 gathers/lane (was 40). Softmax: shuffle-only.
// AV: candidate-parity split across lane halves + shfl_down(32) combine.

__global__ __launch_bounds__(512) void one2many_attn(
    const float* __restrict__ q, const float* __restrict__ k, const float* __restrict__ v,
    const float* __restrict__ K0, const float* __restrict__ K1,
    const float* __restrict__ R, const float* __restrict__ t,
    float* __restrict__ out)
{
#pragma clang fp contract(off)
    __shared__ float s_q[FEAT];
    __shared__ float s_p[NHEAD][CMAX];
    __shared__ int   s_cand[CMAX];
    __shared__ int   s_cnt;
    __shared__ float s_geo[3];   // slope, icpt, mode

    const int l   = blockIdx.x;
    const int tid = threadIdx.x;

    if (tid < FEAT) s_q[tid] = q[l*FEAT + tid];
    if (tid == 0) s_cnt = 0;

    // ---- geometry: wave 0 only (wave-uniform, bit-identical broadcast) ----
    if (tid < 64) {
        float i0[3][3], i1[3][3], A[3][3], B[3][3], T1[3][3], T2[3][3], F[3][3], Rm[3][3];
        np_inv3x3_f32(K0, i0);
        np_inv3x3_f32(K1, i1);
        for (int i=0;i<3;i++)
            for (int j=0;j<3;j++) { A[i][j] = i1[j][i]; Rm[i][j] = R[i*3+j]; }
        const float t0=t[0], t1=t[1], t2=t[2];
        B[0][0]=0.f;  B[0][1]=-t2;  B[0][2]=t1;
        B[1][0]=t2;   B[1][1]=0.f;  B[1][2]=-t0;
        B[2][0]=-t1;  B[2][1]=t0;   B[2][2]=0.f;
        mm3_chain(A,B,T1);      // noblas (swapaxes view)
        mm3_chain(T1,Rm,T2);    // T1 @ I
        mm3_fma(T2,i0,F);       // sgemm FMA

        const float xl = (float)(l % IMG_W);
        const float yl = (float)(l / IMG_W);
        const float la = einsum_row(F[0], xl, yl);
        const float lb = einsum_row(F[1], xl, yl);
        const float lc = einsum_row(F[2], xl, yl);
        const bool  mode  = fabsf(lb) > fabsf(la);
        const float denom = mode ? lb : la;
        const float slope = (mode ? -la : -lb) / denom;
        const float icpt  = (-lc) / denom;
        if (tid == 0) { s_geo[0]=slope; s_geo[1]=icpt; s_geo[2]=mode?1.0f:0.0f; }
    }
    __syncthreads();

    const float slope = s_geo[0];
    const float icpt  = s_geo[1];
    const bool  mode  = (s_geo[2] != 0.0f);

    // ---- candidate collection: identical fp32 band test ----
    for (int m = tid; m < NPIX; m += 512) {
        const float xm = (float)(m % IMG_W), ym = (float)(m / IMG_W);
        const float tin  = mode ? xm : ym;
        const float tchk = mode ? ym : xm;
        const float mu = slope * tin;
        const float cc = mu + icpt;
        const float hi = cc + 2.0f;
        const float lo = cc - 2.0f;
        if ((tchk < hi) && (tchk > lo) && m != 0) {
            int pos = atomicAdd(&s_cnt, 1);
            if (pos < CMAX) s_cand[pos] = m;
        }
    }
    __syncthreads();
    const int nc = min(s_cnt, CMAX);

    const int h    = tid >> 6;     // wave index = head
    const int lane = tid & 63;
    const float* qh = s_q + h*HEAD_DIM;

    // ---- QK: lane handles candidates lane, lane+64, lane+128 ----
    float locmax = -INFINITY;
    for (int c = lane; c < nc; c += 64) {
        const float4* kr = (const float4*)(k + (size_t)s_cand[c]*FEAT + h*HEAD_DIM);
        float acc = 0.f;
        #pragma unroll
        for (int u = 0; u < 8; u++) {
            const float4 kk = kr[u];
            acc = __builtin_fmaf(qh[4*u+0], kk.x, acc);
            acc = __builtin_fmaf(qh[4*u+1], kk.y, acc);
            acc = __builtin_fmaf(qh[4*u+2], kk.z, acc);
            acc = __builtin_fmaf(qh[4*u+3], kk.w, acc);
        }
        const float sc = acc * 0.17677669529663687f;   // 1/sqrt(32)
        s_p[h][c] = sc;
        locmax = fmaxf(locmax, sc);
    }
    // ---- softmax (wave-private: scores written & read by this wave only) ----
    #pragma unroll
    for (int o = 32; o; o >>= 1) locmax = fmaxf(locmax, __shfl_xor(locmax, o));
    float losum = 0.f;
    for (int c = lane; c < nc; c += 64) {
        const float e = __expf(s_p[h][c] - locmax);
        s_p[h][c] = e;
        losum += e;
    }
    #pragma unroll
    for (int o = 32; o; o >>= 1) losum += __shfl_xor(losum, o);

    // ---- AV: lane = dim + 32*parity; coalesced 128B v segments ----
    const int d   = lane & 31;
    const int par = lane >> 5;
    const float* vp = v + h*HEAD_DIM + d;
    float acc = 0.f;
    #pragma unroll 8
    for (int c = par; c < nc; c += 2)
        acc = __builtin_fmaf(s_p[h][c], vp[(size_t)s_cand[c]*FEAT], acc);
    acc += __shfl_down(acc, 32);

    if (lane < 32)
        out[l*FEAT + h*HEAD_DIM + d] = (nc > 0) ? acc / losum : 0.0f;
}

extern "C" void kernel_launch(void* const* d_in, const int* in_sizes, int n_in,
                              void* d_out, int out_size, void* d_ws, size_t ws_size,
                              hipStream_t stream) {
    const float* q  = (const float*)d_in[0];
    const float* k  = (const float*)d_in[1];
    const float* v  = (const float*)d_in[2];
    const float* K0 = (const float*)d_in[3];
    const float* K1 = (const float*)d_in[4];
    const float* R  = (const float*)d_in[5];
    const float* t  = (const float*)d_in[6];
    float* out = (float*)d_out;
    one2many_attn<<<NPIX, 512, 0, stream>>>(q, k, v, K0, K1, R, t, out);
}

// Round 15
// 121.773 us; speedup vs baseline: 1.0600x; 1.0505x over previous
//
#include <hip/hip_runtime.h>
#include <math.h>

#define NHEAD 8
#define HEAD_DIM 32
#define IMG_H 32
#define IMG_W 40
#define NPIX (IMG_H*IMG_W)
#define CMAX 160
#define FEAT (NHEAD*HEAD_DIM)

// ===== Geometry: LOCKED bit-exact numpy-fp32 emulation (R13 PASSED) =====
// M1 chain (swapaxes view -> noblas), M2 chain (T1@I), M3 sgemm-FMA,
// einsum chain, cc chain; ALL under `#pragma clang fp contract(off)`,
// FMA only via __builtin_fmaf. DO NOT TOUCH the semantics below.

__device__ void np_inv3x3_f32(const float* M, float inv[3][3]) {
#pragma clang fp contract(off)
    float A[3][3]; int piv[3];
    for (int i=0;i<3;i++) { A[i][0]=M[i*3+0]; A[i][1]=M[i*3+1]; A[i][2]=M[i*3+2]; }
    for (int kk=0;kk<3;kk++) {
        int p = kk;
        float colmax = fabsf(A[kk][kk]);
        for (int i=kk+1;i<3;i++) { float vv=fabsf(A[i][kk]); if (vv>colmax){colmax=vv;p=i;} }
        piv[kk] = p;
        if (p!=kk) { for(int j=0;j<3;j++){float tmp=A[kk][j];A[kk][j]=A[p][j];A[p][j]=tmp;} }
        const float rp = 1.0f / A[kk][kk];
        for (int i=kk+1;i<3;i++) A[i][kk] = A[i][kk] * rp;
        for (int i=kk+1;i<3;i++)
            for (int j=kk+1;j<3;j++)
                A[i][j] = A[i][j] - A[i][kk]*A[kk][j];
    }
    for (int col=0; col<3; col++) {
        float b[3] = {0.f,0.f,0.f}; b[col] = 1.0f;
        for (int kk=0;kk<3;kk++) if (piv[kk]!=kk) { float tmp=b[kk]; b[kk]=b[piv[kk]]; b[piv[kk]]=tmp; }
        for (int i=1;i<3;i++)
            for (int kk=0;kk<i;kk++)
                b[i] = b[i] - A[i][kk]*b[kk];
        for (int kk=2;kk>=0;kk--) {
            b[kk] = b[kk] / A[kk][kk];
            for (int i=0;i<kk;i++)
                b[i] = b[i] - A[i][kk]*b[kk];
        }
        inv[0][col]=b[0]; inv[1][col]=b[1]; inv[2][col]=b[2];
    }
}

__device__ void mm3_chain(const float A[3][3], const float B[3][3], float C[3][3]) {
#pragma clang fp contract(off)
    for (int i=0;i<3;i++)
        for (int j=0;j<3;j++) {
            float acc = A[i][0]*B[0][j];
            acc = acc + A[i][1]*B[1][j];
            acc = acc + A[i][2]*B[2][j];
            C[i][j] = acc;
        }
}
__device__ void mm3_fma(const float A[3][3], const float B[3][3], float C[3][3]) {
#pragma clang fp contract(off)
    for (int i=0;i<3;i++)
        for (int j=0;j<3;j++) {
            float acc = A[i][0]*B[0][j];
            acc = __builtin_fmaf(A[i][1], B[1][j], acc);
            acc = __builtin_fmaf(A[i][2], B[2][j], acc);
            C[i][j] = acc;
        }
}
__device__ float einsum_row(const float Fi[3], float x, float y) {
#pragma clang fp contract(off)
    float acc = Fi[0]*x;
    acc = acc + Fi[1]*y;
    acc = acc + Fi[2]*1.0f;
    return acc;
}

// ===== R15: coalesce the QK gather =====
// R14 counters: occupancy +60% -> 0 speedup; VALUBusy 19%; nothing
// saturated => per-CU L1/TA serialization on scattered lanes (candidate-
// per-lane QK: 64 lines per wave-load). New QK: 8 candidates x 8 lanes
// x 4 dims -> 16 lines per wave-load + shfl_xor tree dot. AV: contiguous
// half-split so LDS reads vectorize.

__global__ __launch_bounds__(512) void one2many_attn(
    const float* __restrict__ q, const float* __restrict__ k, const float* __restrict__ v,
    const float* __restrict__ K0, const float* __restrict__ K1,
    const float* __restrict__ R, const float* __restrict__ t,
    float* __restrict__ out)
{
#pragma clang fp contract(off)
    __shared__ float s_q[FEAT];
    __shared__ float s_p[NHEAD][CMAX];
    __shared__ int   s_cand[CMAX];
    __shared__ int   s_cnt;
    __shared__ float s_geo[3];   // slope, icpt, mode

    const int l   = blockIdx.x;
    const int tid = threadIdx.x;

    if (tid < FEAT) s_q[tid] = q[l*FEAT + tid];
    if (tid == 0) s_cnt = 0;

    // ---- geometry: wave 0 only (wave-uniform, bit-identical broadcast) ----
    if (tid < 64) {
        float i0[3][3], i1[3][3], A[3][3], B[3][3], T1[3][3], T2[3][3], F[3][3], Rm[3][3];
        np_inv3x3_f32(K0, i0);
        np_inv3x3_f32(K1, i1);
        for (int i=0;i<3;i++)
            for (int j=0;j<3;j++) { A[i][j] = i1[j][i]; Rm[i][j] = R[i*3+j]; }
        const float t0=t[0], t1=t[1], t2=t[2];
        B[0][0]=0.f;  B[0][1]=-t2;  B[0][2]=t1;
        B[1][0]=t2;   B[1][1]=0.f;  B[1][2]=-t0;
        B[2][0]=-t1;  B[2][1]=t0;   B[2][2]=0.f;
        mm3_chain(A,B,T1);      // noblas (swapaxes view)
        mm3_chain(T1,Rm,T2);    // T1 @ I
        mm3_fma(T2,i0,F);       // sgemm FMA

        const float xl = (float)(l % IMG_W);
        const float yl = (float)(l / IMG_W);
        const float la = einsum_row(F[0], xl, yl);
        const float lb = einsum_row(F[1], xl, yl);
        const float lc = einsum_row(F[2], xl, yl);
        const bool  mode  = fabsf(lb) > fabsf(la);
        const float denom = mode ? lb : la;
        const float slope = (mode ? -la : -lb) / denom;
        const float icpt  = (-lc) / denom;
        if (tid == 0) { s_geo[0]=slope; s_geo[1]=icpt; s_geo[2]=mode?1.0f:0.0f; }
    }
    __syncthreads();

    const float slope = s_geo[0];
    const float icpt  = s_geo[1];
    const bool  mode  = (s_geo[2] != 0.0f);

    // ---- candidate collection: identical fp32 band test ----
    for (int m = tid; m < NPIX; m += 512) {
        const float xm = (float)(m % IMG_W), ym = (float)(m / IMG_W);
        const float tin  = mode ? xm : ym;
        const float tchk = mode ? ym : xm;
        const float mu = slope * tin;
        const float cc = mu + icpt;
        const float hi = cc + 2.0f;
        const float lo = cc - 2.0f;
        if ((tchk < hi) && (tchk > lo) && m != 0) {
            int pos = atomicAdd(&s_cnt, 1);
            if (pos < CMAX) s_cand[pos] = m;
        }
    }
    __syncthreads();
    const int nc = min(s_cnt, CMAX);

    const int h    = tid >> 6;     // wave index = head
    const int lane = tid & 63;

    // ---- QK: 8 candidates per wave-load (16 cache lines, was 64) ----
    const int grp = lane >> 3;          // candidate sub-index 0..7
    const int dj  = (lane & 7) << 2;    // dim offset 0,4,...,28
    const float q0 = s_q[h*HEAD_DIM + dj + 0];
    const float q1 = s_q[h*HEAD_DIM + dj + 1];
    const float q2 = s_q[h*HEAD_DIM + dj + 2];
    const float q3 = s_q[h*HEAD_DIM + dj + 3];
    #pragma unroll 4
    for (int base = 0; base < nc; base += 8) {
        const int cc  = base + grp;
        const int row = (cc < nc) ? s_cand[cc] : s_cand[0];   // safe: nc>=1 inside loop
        const float4 kk = *(const float4*)(k + (size_t)row*FEAT + h*HEAD_DIM + dj);
        float p = q0*kk.x;
        p = __builtin_fmaf(q1, kk.y, p);
        p = __builtin_fmaf(q2, kk.z, p);
        p = __builtin_fmaf(q3, kk.w, p);
        p += __shfl_xor(p, 1);
        p += __shfl_xor(p, 2);
        p += __shfl_xor(p, 4);              // full dot in every lane of the 8-group
        if (((lane & 7) == 0) && cc < nc)
            s_p[h][cc] = p * 0.17677669529663687f;   // 1/sqrt(32)
    }

    // ---- softmax (wave-private; same wave wrote s_p[h][*]) ----
    float mx = -INFINITY;
    for (int c = lane; c < nc; c += 64) mx = fmaxf(mx, s_p[h][c]);
    #pragma unroll
    for (int o = 32; o; o >>= 1) mx = fmaxf(mx, __shfl_xor(mx, o));
    float sum = 0.f;
    for (int c = lane; c < nc; c += 64) {
        const float e = __expf(s_p[h][c] - mx);
        s_p[h][c] = e;
        sum += e;
    }
    #pragma unroll
    for (int o = 32; o; o >>= 1) sum += __shfl_xor(sum, o);

    // ---- AV: contiguous half-split (vectorizable LDS reads, 4-line gathers) ----
    const int d   = lane & 31;
    const int par = lane >> 5;
    const int hn  = (nc + 1) >> 1;
    const int c0  = par * hn;
    const int c1  = min(nc, c0 + hn);
    const float* vp = v + h*HEAD_DIM + d;
    float acc = 0.f;
    #pragma unroll 8
    for (int c = c0; c < c1; c++)
        acc = __builtin_fmaf(s_p[h][c], vp[(size_t)s_cand[c]*FEAT], acc);
    acc += __shfl_down(acc, 32);

    if (lane < 32)
        out[l*FEAT + h*HEAD_DIM + d] = (nc > 0) ? acc / sum : 0.0f;
}

extern "C" void kernel_launch(void* const* d_in, const int* in_sizes, int n_in,
                              void* d_out, int out_size, void* d_ws, size_t ws_size,
                              hipStream_t stream) {
    const float* q  = (const float*)d_in[0];
    const float* k  = (const float*)d_in[1];
    const float* v  = (const float*)d_in[2];
    const float* K0 = (const float*)d_in[3];
    const float* K1 = (const float*)d_in[4];
    const float* R  = (const float*)d_in[5];
    const float* t  = (const float*)d_in[6];
    float* out = (float*)d_out;
    one2many_attn<<<NPIX, 512, 0, stream>>>(q, k, v, K0, K1, R, t, out);
}

// Round 17
// 117.608 us; speedup vs baseline: 1.0976x; 1.0354x over previous
//
#include <hip/hip_runtime.h>
#include <math.h>

#define NHEAD 8
#define HEAD_DIM 32
#define IMG_H 32
#define IMG_W 40
#define NPIX (IMG_H*IMG_W)
#define CMAX 160
#define NITER (CMAX/8)   // 20
#define FEAT (NHEAD*HEAD_DIM)

// ===== Geometry: LOCKED bit-exact numpy-fp32 emulation (R13 PASSED) =====
// M1 chain (swapaxes view -> noblas), M2 chain (T1@I), M3 sgemm-FMA,
// einsum chain, cc chain; ALL under `#pragma clang fp contract(off)`,
// FMA only via __builtin_fmaf. DO NOT TOUCH the semantics below.

__device__ void np_inv3x3_f32(const float* M, float inv[3][3]) {
#pragma clang fp contract(off)
    float A[3][3]; int piv[3];
    for (int i=0;i<3;i++) { A[i][0]=M[i*3+0]; A[i][1]=M[i*3+1]; A[i][2]=M[i*3+2]; }
    for (int kk=0;kk<3;kk++) {
        int p = kk;
        float colmax = fabsf(A[kk][kk]);
        for (int i=kk+1;i<3;i++) { float vv=fabsf(A[i][kk]); if (vv>colmax){colmax=vv;p=i;} }
        piv[kk] = p;
        if (p!=kk) { for(int j=0;j<3;j++){float tmp=A[kk][j];A[kk][j]=A[p][j];A[p][j]=tmp;} }
        const float rp = 1.0f / A[kk][kk];
        for (int i=kk+1;i<3;i++) A[i][kk] = A[i][kk] * rp;
        for (int i=kk+1;i<3;i++)
            for (int j=kk+1;j<3;j++)
                A[i][j] = A[i][j] - A[i][kk]*A[kk][j];
    }
    for (int col=0; col<3; col++) {
        float b[3] = {0.f,0.f,0.f}; b[col] = 1.0f;
        for (int kk=0;kk<3;kk++) if (piv[kk]!=kk) { float tmp=b[kk]; b[kk]=b[piv[kk]]; b[piv[kk]]=tmp; }
        for (int i=1;i<3;i++)
            for (int kk=0;kk<i;kk++)
                b[i] = b[i] - A[i][kk]*b[kk];
        for (int kk=2;kk>=0;kk--) {
            b[kk] = b[kk] / A[kk][kk];
            for (int i=0;i<kk;i++)
                b[i] = b[i] - A[i][kk]*b[kk];
        }
        inv[0][col]=b[0]; inv[1][col]=b[1]; inv[2][col]=b[2];
    }
}

__device__ void mm3_chain(const float A[3][3], const float B[3][3], float C[3][3]) {
#pragma clang fp contract(off)
    for (int i=0;i<3;i++)
        for (int j=0;j<3;j++) {
            float acc = A[i][0]*B[0][j];
            acc = acc + A[i][1]*B[1][j];
            acc = acc + A[i][2]*B[2][j];
            C[i][j] = acc;
        }
}
__device__ void mm3_fma(const float A[3][3], const float B[3][3], float C[3][3]) {
#pragma clang fp contract(off)
    for (int i=0;i<3;i++)
        for (int j=0;j<3;j++) {
            float acc = A[i][0]*B[0][j];
            acc = __builtin_fmaf(A[i][1], B[1][j], acc);
            acc = __builtin_fmaf(A[i][2], B[2][j], acc);
            C[i][j] = acc;
        }
}
__device__ float einsum_row(const float Fi[3], float x, float y) {
#pragma clang fp contract(off)
    float acc = Fi[0]*x;
    acc = acc + Fi[1]*y;
    acc = acc + Fi[2]*1.0f;
    return acc;
}

// ===== R17: register-resident scores + float4 AV (R16 resubmit; infra fail) =====
// Model: per-CU TA slots ~ VMEM wave-instructions x unique lines. R15 had
// QK=20 dwordx4 + AV=77 scalar dwords per wave. Here both phases use the
// 8-cand x 8-lane x float4 layout: 40 dwordx4 total, scores/weights live
// in registers (LDS score array deleted), softmax denominator = wave-sum/8
// (exact: all 8 lanes of a group hold identical e), AV float4 partials
// reduced by stride-8/16/32 shuffles, float4 stores from lanes 0..7.

__global__ __launch_bounds__(512) void one2many_attn(
    const float* __restrict__ q, const float* __restrict__ k, const float* __restrict__ v,
    const float* __restrict__ K0, const float* __restrict__ K1,
    const float* __restrict__ R, const float* __restrict__ t,
    float* __restrict__ out)
{
#pragma clang fp contract(off)
    __shared__ float s_q[FEAT];
    __shared__ int   s_cand[CMAX];
    __shared__ int   s_cnt;
    __shared__ float s_geo[3];   // slope, icpt, mode

    const int l   = blockIdx.x;
    const int tid = threadIdx.x;

    if (tid < FEAT) s_q[tid] = q[l*FEAT + tid];
    if (tid == 0) s_cnt = 0;

    // ---- geometry: wave 0 only (wave-uniform, bit-identical broadcast) ----
    if (tid < 64) {
        float i0[3][3], i1[3][3], A[3][3], B[3][3], T1[3][3], T2[3][3], F[3][3], Rm[3][3];
        np_inv3x3_f32(K0, i0);
        np_inv3x3_f32(K1, i1);
        for (int i=0;i<3;i++)
            for (int j=0;j<3;j++) { A[i][j] = i1[j][i]; Rm[i][j] = R[i*3+j]; }
        const float t0=t[0], t1=t[1], t2=t[2];
        B[0][0]=0.f;  B[0][1]=-t2;  B[0][2]=t1;
        B[1][0]=t2;   B[1][1]=0.f;  B[1][2]=-t0;
        B[2][0]=-t1;  B[2][1]=t0;   B[2][2]=0.f;
        mm3_chain(A,B,T1);      // noblas (swapaxes view)
        mm3_chain(T1,Rm,T2);    // T1 @ I
        mm3_fma(T2,i0,F);       // sgemm FMA

        const float xl = (float)(l % IMG_W);
        const float yl = (float)(l / IMG_W);
        const float la = einsum_row(F[0], xl, yl);
        const float lb = einsum_row(F[1], xl, yl);
        const float lc = einsum_row(F[2], xl, yl);
        const bool  mode  = fabsf(lb) > fabsf(la);
        const float denom = mode ? lb : la;
        const float slope = (mode ? -la : -lb) / denom;
        const float icpt  = (-lc) / denom;
        if (tid == 0) { s_geo[0]=slope; s_geo[1]=icpt; s_geo[2]=mode?1.0f:0.0f; }
    }
    __syncthreads();

    const float slope = s_geo[0];
    const float icpt  = s_geo[1];
    const bool  mode  = (s_geo[2] != 0.0f);

    // ---- candidate collection: identical fp32 band test ----
    for (int m = tid; m < NPIX; m += 512) {
        const float xm = (float)(m % IMG_W), ym = (float)(m / IMG_W);
        const float tin  = mode ? xm : ym;
        const float tchk = mode ? ym : xm;
        const float mu = slope * tin;
        const float cc = mu + icpt;
        const float hi = cc + 2.0f;
        const float lo = cc - 2.0f;
        if ((tchk < hi) && (tchk > lo) && m != 0) {
            int pos = atomicAdd(&s_cnt, 1);
            if (pos < CMAX) s_cand[pos] = m;
        }
    }
    __syncthreads();
    const int nc = min(s_cnt, CMAX);

    const int h    = tid >> 6;          // wave index = head
    const int lane = tid & 63;
    const int grp  = lane >> 3;         // candidate sub-index within 8-group
    const int dj   = (lane & 7) << 2;   // dim offset 0,4,...,28

    const float4 q4 = *(const float4*)(s_q + h*HEAD_DIM + dj);
    const float* kh = k + h*HEAD_DIM + dj;
    const float* vh = v + h*HEAD_DIM + dj;

    // ---- QK: scores into registers (lane owns candidates grp, grp+8, ...) ----
    int   rows[NITER];
    float sc[NITER];
    #pragma unroll
    for (int i = 0; i < NITER; i++) {
        const int ci = (i << 3) + grp;
        rows[i] = s_cand[(ci < nc) ? ci : 0];
        const float4 kk = *(const float4*)(kh + (size_t)rows[i]*FEAT);
        float p = q4.x*kk.x;
        p = __builtin_fmaf(q4.y, kk.y, p);
        p = __builtin_fmaf(q4.z, kk.z, p);
        p = __builtin_fmaf(q4.w, kk.w, p);
        p += __shfl_xor(p, 1);
        p += __shfl_xor(p, 2);
        p += __shfl_xor(p, 4);              // full dot, identical across 8-group
        sc[i] = (ci < nc) ? p * 0.17677669529663687f : -INFINITY;
    }

    // ---- softmax in registers; denominator = wave-sum / 8 (exact) ----
    float mx = -INFINITY;
    #pragma unroll
    for (int i = 0; i < NITER; i++) mx = fmaxf(mx, sc[i]);
    #pragma unroll
    for (int o = 32; o; o >>= 1) mx = fmaxf(mx, __shfl_xor(mx, o));
    float losum = 0.f;
    #pragma unroll
    for (int i = 0; i < NITER; i++) {
        const float e = __expf(sc[i] - mx);   // expf(-inf)=0 masks invalid slots
        sc[i] = e;
        losum += e;
    }
    #pragma unroll
    for (int o = 32; o; o >>= 1) losum += __shfl_xor(losum, o);
    const float sum = losum * 0.125f;         // each candidate counted 8x

    // ---- AV: float4 partials per lane, stride-8 shuffle reduce ----
    float ax = 0.f, ay = 0.f, az = 0.f, aw = 0.f;
    #pragma unroll
    for (int i = 0; i < NITER; i++) {
        const float4 vv = *(const float4*)(vh + (size_t)rows[i]*FEAT);
        ax = __builtin_fmaf(sc[i], vv.x, ax);
        ay = __builtin_fmaf(sc[i], vv.y, ay);
        az = __builtin_fmaf(sc[i], vv.z, az);
        aw = __builtin_fmaf(sc[i], vv.w, aw);
    }
    #pragma unroll
    for (int o = 8; o <= 32; o <<= 1) {
        ax += __shfl_xor(ax, o);
        ay += __shfl_xor(ay, o);
        az += __shfl_xor(az, o);
        aw += __shfl_xor(aw, o);
    }

    if (lane < 8) {
        float4 r;
        if (nc > 0) { r.x = ax/sum; r.y = ay/sum; r.z = az/sum; r.w = aw/sum; }
        else        { r.x = r.y = r.z = r.w = 0.0f; }
        *(float4*)(out + l*FEAT + h*HEAD_DIM + dj) = r;
    }
}

extern "C" void kernel_launch(void* const* d_in, const int* in_sizes, int n_in,
                              void* d_out, int out_size, void* d_ws, size_t ws_size,
                              hipStream_t stream) {
    const float* q  = (const float*)d_in[0];
    const float* k  = (const float*)d_in[1];
    const float* v  = (const float*)d_in[2];
    const float* K0 = (const float*)d_in[3];
    const float* K1 = (const float*)d_in[4];
    const float* R  = (const float*)d_in[5];
    const float* t  = (const float*)d_in[6];
    float* out = (float*)d_out;
    one2many_attn<<<NPIX, 512, 0, stream>>>(q, k, v, K0, K1, R, t, out);
}

// Round 18
// 95.738 us; speedup vs baseline: 1.3483x; 1.2284x over previous
//
#include <hip/hip_runtime.h>
#include <math.h>

#define NHEAD 8
#define HEAD_DIM 32
#define IMG_H 32
#define IMG_W 40
#define NPIX (IMG_H*IMG_W)
#define CMAX 160
#define NITER (CMAX/8)   // 20
#define FEAT (NHEAD*HEAD_DIM)

// ===== Geometry: LOCKED bit-exact numpy-fp32 emulation (R13 PASSED) =====
// M1 chain (noblas), M2 chain, M3 sgemm-FMA, einsum chain, cc chain; all
// under `#pragma clang fp contract(off)`, FMA only via __builtin_fmaf.

__device__ void np_inv3x3_f32(const float* M, float inv[3][3]) {
#pragma clang fp contract(off)
    float A[3][3]; int piv[3];
    for (int i=0;i<3;i++) { A[i][0]=M[i*3+0]; A[i][1]=M[i*3+1]; A[i][2]=M[i*3+2]; }
    for (int kk=0;kk<3;kk++) {
        int p = kk;
        float colmax = fabsf(A[kk][kk]);
        for (int i=kk+1;i<3;i++) { float vv=fabsf(A[i][kk]); if (vv>colmax){colmax=vv;p=i;} }
        piv[kk] = p;
        if (p!=kk) { for(int j=0;j<3;j++){float tmp=A[kk][j];A[kk][j]=A[p][j];A[p][j]=tmp;} }
        const float rp = 1.0f / A[kk][kk];
        for (int i=kk+1;i<3;i++) A[i][kk] = A[i][kk] * rp;
        for (int i=kk+1;i<3;i++)
            for (int j=kk+1;j<3;j++)
                A[i][j] = A[i][j] - A[i][kk]*A[kk][j];
    }
    for (int col=0; col<3; col++) {
        float b[3] = {0.f,0.f,0.f}; b[col] = 1.0f;
        for (int kk=0;kk<3;kk++) if (piv[kk]!=kk) { float tmp=b[kk]; b[kk]=b[piv[kk]]; b[piv[kk]]=tmp; }
        for (int i=1;i<3;i++)
            for (int kk=0;kk<i;kk++)
                b[i] = b[i] - A[i][kk]*b[kk];
        for (int kk=2;kk>=0;kk--) {
            b[kk] = b[kk] / A[kk][kk];
            for (int i=0;i<kk;i++)
                b[i] = b[i] - A[i][kk]*b[kk];
        }
        inv[0][col]=b[0]; inv[1][col]=b[1]; inv[2][col]=b[2];
    }
}

__device__ void mm3_chain(const float A[3][3], const float B[3][3], float C[3][3]) {
#pragma clang fp contract(off)
    for (int i=0;i<3;i++)
        for (int j=0;j<3;j++) {
            float acc = A[i][0]*B[0][j];
            acc = acc + A[i][1]*B[1][j];
            acc = acc + A[i][2]*B[2][j];
            C[i][j] = acc;
        }
}
__device__ void mm3_fma(const float A[3][3], const float B[3][3], float C[3][3]) {
#pragma clang fp contract(off)
    for (int i=0;i<3;i++)
        for (int j=0;j<3;j++) {
            float acc = A[i][0]*B[0][j];
            acc = __builtin_fmaf(A[i][1], B[1][j], acc);
            acc = __builtin_fmaf(A[i][2], B[2][j], acc);
            C[i][j] = acc;
        }
}
__device__ float einsum_row(const float Fi[3], float x, float y) {
#pragma clang fp contract(off)
    float acc = Fi[0]*x;
    acc = acc + Fi[1]*y;
    acc = acc + Fi[2]*1.0f;
    return acc;
}

// ===== R18: split geometry out of the 1280-block hot path =====
// R13-R17 invariance (58-68 us across radically different attention
// layouts, VALUBusy pinned ~19%, occupancy inert) => the serial per-block
// preamble (wave0-only geometry: ~24 fp32 divides, 7 waves parked at the
// barrier) dominates. K1 computes per-l {slope,icpt,mode} once into ws;
// K2 replaces geometry with one broadcast float4 load.

__global__ __launch_bounds__(64) void geo_kernel(
    const float* __restrict__ K0, const float* __restrict__ K1,
    const float* __restrict__ R, const float* __restrict__ t,
    float4* __restrict__ geo)
{
#pragma clang fp contract(off)
    const int l = blockIdx.x * 64 + threadIdx.x;   // 20*64 = 1280 exactly
    float i0[3][3], i1[3][3], A[3][3], B[3][3], T1[3][3], T2[3][3], F[3][3], Rm[3][3];
    np_inv3x3_f32(K0, i0);
    np_inv3x3_f32(K1, i1);
    for (int i=0;i<3;i++)
        for (int j=0;j<3;j++) { A[i][j] = i1[j][i]; Rm[i][j] = R[i*3+j]; }
    const float t0=t[0], t1=t[1], t2=t[2];
    B[0][0]=0.f;  B[0][1]=-t2;  B[0][2]=t1;
    B[1][0]=t2;   B[1][1]=0.f;  B[1][2]=-t0;
    B[2][0]=-t1;  B[2][1]=t0;   B[2][2]=0.f;
    mm3_chain(A,B,T1);      // noblas (swapaxes view)
    mm3_chain(T1,Rm,T2);    // T1 @ I
    mm3_fma(T2,i0,F);       // sgemm FMA

    const float xl = (float)(l % IMG_W);
    const float yl = (float)(l / IMG_W);
    const float la = einsum_row(F[0], xl, yl);
    const float lb = einsum_row(F[1], xl, yl);
    const float lc = einsum_row(F[2], xl, yl);
    const bool  mode  = fabsf(lb) > fabsf(la);
    const float denom = mode ? lb : la;
    const float slope = (mode ? -la : -lb) / denom;
    const float icpt  = (-lc) / denom;
    geo[l] = make_float4(slope, icpt, mode ? 1.0f : 0.0f, 0.0f);
}

__global__ __launch_bounds__(512) void one2many_attn(
    const float* __restrict__ q, const float* __restrict__ k, const float* __restrict__ v,
    const float4* __restrict__ geo, float* __restrict__ out)
{
#pragma clang fp contract(off)
    __shared__ float s_q[FEAT];
    __shared__ int   s_cand[CMAX];
    __shared__ int   s_cnt;

    const int l   = blockIdx.x;
    const int tid = threadIdx.x;

    if (tid < FEAT) s_q[tid] = q[l*FEAT + tid];
    if (tid == 0) s_cnt = 0;

    const float4 g = geo[l];            // broadcast load (L1/L2-resident)
    const float slope = g.x;
    const float icpt  = g.y;
    const bool  mode  = (g.z != 0.0f);
    __syncthreads();   // s_cnt=0 visible

    // ---- candidate collection: identical fp32 band test ----
    for (int m = tid; m < NPIX; m += 512) {
        const float xm = (float)(m % IMG_W), ym = (float)(m / IMG_W);
        const float tin  = mode ? xm : ym;
        const float tchk = mode ? ym : xm;
        const float mu = slope * tin;
        const float cc = mu + icpt;
        const float hi = cc + 2.0f;
        const float lo = cc - 2.0f;
        if ((tchk < hi) && (tchk > lo) && m != 0) {
            int pos = atomicAdd(&s_cnt, 1);
            if (pos < CMAX) s_cand[pos] = m;
        }
    }
    __syncthreads();
    const int nc = min(s_cnt, CMAX);

    const int h    = tid >> 6;          // wave index = head
    const int lane = tid & 63;
    const int grp  = lane >> 3;         // candidate sub-index within 8-group
    const int dj   = (lane & 7) << 2;   // dim offset 0,4,...,28

    const float4 q4 = *(const float4*)(s_q + h*HEAD_DIM + dj);
    const float* kh = k + h*HEAD_DIM + dj;
    const float* vh = v + h*HEAD_DIM + dj;

    // ---- QK: scores into registers (lane owns candidates grp, grp+8, ...) ----
    int   rows[NITER];
    float sc[NITER];
    #pragma unroll
    for (int i = 0; i < NITER; i++) {
        const int ci = (i << 3) + grp;
        rows[i] = s_cand[(ci < nc) ? ci : 0];
        const float4 kk = *(const float4*)(kh + (size_t)rows[i]*FEAT);
        float p = q4.x*kk.x;
        p = __builtin_fmaf(q4.y, kk.y, p);
        p = __builtin_fmaf(q4.z, kk.z, p);
        p = __builtin_fmaf(q4.w, kk.w, p);
        p += __shfl_xor(p, 1);
        p += __shfl_xor(p, 2);
        p += __shfl_xor(p, 4);              // full dot, identical across 8-group
        sc[i] = (ci < nc) ? p * 0.17677669529663687f : -INFINITY;
    }

    // ---- softmax in registers; denominator = wave-sum / 8 (exact) ----
    float mx = -INFINITY;
    #pragma unroll
    for (int i = 0; i < NITER; i++) mx = fmaxf(mx, sc[i]);
    #pragma unroll
    for (int o = 32; o; o >>= 1) mx = fmaxf(mx, __shfl_xor(mx, o));
    float losum = 0.f;
    #pragma unroll
    for (int i = 0; i < NITER; i++) {
        const float e = __expf(sc[i] - mx);   // expf(-inf)=0 masks invalid slots
        sc[i] = e;
        losum += e;
    }
    #pragma unroll
    for (int o = 32; o; o >>= 1) losum += __shfl_xor(losum, o);
    const float sum = losum * 0.125f;         // each candidate counted 8x

    // ---- AV: float4 partials per lane, stride-8 shuffle reduce ----
    float ax = 0.f, ay = 0.f, az = 0.f, aw = 0.f;
    #pragma unroll
    for (int i = 0; i < NITER; i++) {
        const float4 vv = *(const float4*)(vh + (size_t)rows[i]*FEAT);
        ax = __builtin_fmaf(sc[i], vv.x, ax);
        ay = __builtin_fmaf(sc[i], vv.y, ay);
        az = __builtin_fmaf(sc[i], vv.z, az);
        aw = __builtin_fmaf(sc[i], vv.w, aw);
    }
    #pragma unroll
    for (int o = 8; o <= 32; o <<= 1) {
        ax += __shfl_xor(ax, o);
        ay += __shfl_xor(ay, o);
        az += __shfl_xor(az, o);
        aw += __shfl_xor(aw, o);
    }

    if (lane < 8) {
        float4 r;
        if (nc > 0) { r.x = ax/sum; r.y = ay/sum; r.z = az/sum; r.w = aw/sum; }
        else        { r.x = r.y = r.z = r.w = 0.0f; }
        *(float4*)(out + l*FEAT + h*HEAD_DIM + dj) = r;
    }
}

extern "C" void kernel_launch(void* const* d_in, const int* in_sizes, int n_in,
                              void* d_out, int out_size, void* d_ws, size_t ws_size,
                              hipStream_t stream) {
    const float* q  = (const float*)d_in[0];
    const float* k  = (const float*)d_in[1];
    const float* v  = (const float*)d_in[2];
    const float* K0 = (const float*)d_in[3];
    const float* K1 = (const float*)d_in[4];
    const float* R  = (const float*)d_in[5];
    const float* t  = (const float*)d_in[6];
    float* out = (float*)d_out;
    float4* geo = (float4*)d_ws;        // 1280 x 16 B = 20 KB
    geo_kernel<<<NPIX/64, 64, 0, stream>>>(K0, K1, R, t, geo);
    one2many_attn<<<NPIX, 512, 0, stream>>>(q, k, v, geo, out);
}